// Round 1
// baseline (354.338 us; speedup 1.0000x reference)
//
#include <hip/hip_runtime.h>
#include <float.h>
#include <math.h>

// QuadrupletLoss fused kernel, round 1: f32 vector-ALU flash-style row stats.
// B=8192, D=128, 50 classes. Loss = -(1/B) * sum_c count[c] * lp_c.

constexpr int B_N  = 8192;
constexpr int D_K  = 128;
constexpr int NCLS = 50;
constexpr int BM = 64;
constexpr int BN = 64;
constexpr int NCHUNK = 4;               // column chunks -> 512 blocks total
constexpr int CHUNK  = B_N / NCHUNK;    // 2048 columns per chunk
constexpr float TEMP_INV = 20.0f;       // 1/0.05 (reference hardcodes 0.05)

__device__ __forceinline__ void online_combine(float& m, float& s, float m2, float s2) {
    // safe when either side is (-FLT_MAX, 0)
    float nm = fmaxf(m, m2);
    s = s * __expf(m - nm) + s2 * __expf(m2 - nm);
    m = nm;
}

// swizzled LDS float-index for (row, kq) where kq indexes float4 groups 0..31
__device__ __forceinline__ int swz_idx(int row, int kq) {
    return row * D_K + ((kq ^ ((row >> 2) & 7)) << 2);
}

__global__ __launch_bounds__(256, 2)
void rowstats_kernel(const float* __restrict__ anchor,
                     const float* __restrict__ target,
                     const int*   __restrict__ labels,
                     float* __restrict__ pmx, float* __restrict__ ps)
{
    __shared__ float aT[BM * D_K];
    __shared__ float bT[BN * D_K];
    __shared__ int   labB[BN];

    const int chunk  = blockIdx.x;
    const int rowBlk = blockIdx.y * BM;
    const int tid = threadIdx.x;
    const int ty = tid >> 4, tx = tid & 15;
    const int r0 = ty * 4, c0 = tx * 4;

    // Stage anchor tile once (swizzled). 64 rows x 32 float4s.
    for (int f = tid; f < BM * (D_K / 4); f += 256) {
        int row = f >> 5, kq = f & 31;
        float4 v = *reinterpret_cast<const float4*>(anchor + (size_t)(rowBlk + row) * D_K + (kq << 2));
        *reinterpret_cast<float4*>(&aT[swz_idx(row, kq)]) = v;
    }

    int labA[4];
#pragma unroll
    for (int i = 0; i < 4; ++i) labA[i] = labels[rowBlk + r0 + i];

    // per-row online (max, sum); base indices with own-row swizzle folded in
    float mx[4], sm[4];
    int aBase[4], bBase[4];
#pragma unroll
    for (int i = 0; i < 4; ++i) {
        mx[i] = -FLT_MAX; sm[i] = 0.0f;
        int row = r0 + i;
        aBase[i] = row * D_K + (((row >> 2) & 7) << 2);   // XOR with kq*4 gives logical-kq slot
        row = c0 + i;
        bBase[i] = row * D_K + (((row >> 2) & 7) << 2);
    }

    for (int mt = 0; mt < CHUNK; mt += BN) {
        const int mBase = chunk * CHUNK + mt;
        __syncthreads();   // previous tile's reads done before overwrite
        for (int f = tid; f < BN * (D_K / 4); f += 256) {
            int row = f >> 5, kq = f & 31;
            float4 v = *reinterpret_cast<const float4*>(target + (size_t)(mBase + row) * D_K + (kq << 2));
            *reinterpret_cast<float4*>(&bT[swz_idx(row, kq)]) = v;
        }
        if (tid < BN) labB[tid] = labels[mBase + tid];
        __syncthreads();

        float acc[4][4];
#pragma unroll
        for (int i = 0; i < 4; ++i)
#pragma unroll
            for (int j = 0; j < 4; ++j) acc[i][j] = 0.0f;

#pragma unroll 8
        for (int kq = 0; kq < D_K / 4; ++kq) {
            float4 af[4], bf[4];
#pragma unroll
            for (int i = 0; i < 4; ++i)
                af[i] = *reinterpret_cast<const float4*>(&aT[aBase[i] ^ (kq << 2)]);
#pragma unroll
            for (int j = 0; j < 4; ++j)
                bf[j] = *reinterpret_cast<const float4*>(&bT[bBase[j] ^ (kq << 2)]);
#pragma unroll
            for (int i = 0; i < 4; ++i)
#pragma unroll
                for (int j = 0; j < 4; ++j) {
                    acc[i][j] = fmaf(af[i].x, bf[j].x, acc[i][j]);
                    acc[i][j] = fmaf(af[i].y, bf[j].y, acc[i][j]);
                    acc[i][j] = fmaf(af[i].z, bf[j].z, acc[i][j]);
                    acc[i][j] = fmaf(af[i].w, bf[j].w, acc[i][j]);
                }
        }

        int lB[4];
#pragma unroll
        for (int j = 0; j < 4; ++j) lB[j] = labB[c0 + j];
#pragma unroll
        for (int i = 0; i < 4; ++i) {
#pragma unroll
            for (int j = 0; j < 4; ++j) {
                bool valid = (lB[j] != labA[i]);
                float v = valid ? acc[i][j] * TEMP_INV : -FLT_MAX;
                if (v > mx[i]) {                  // first valid hit: sm*exp(-huge)=0, +1
                    sm[i] = sm[i] * __expf(mx[i] - v) + 1.0f;
                    mx[i] = v;
                } else if (valid) {
                    sm[i] += __expf(v - mx[i]);
                }
            }
        }
    }

    // reduce (mx, sm) across the 16 tx-lanes (same wave, xor of low 4 lane bits)
#pragma unroll
    for (int i = 0; i < 4; ++i) {
#pragma unroll
        for (int off = 1; off < 16; off <<= 1) {
            float m2 = __shfl_xor(mx[i], off);
            float s2 = __shfl_xor(sm[i], off);
            online_combine(mx[i], sm[i], m2, s2);
        }
        if (tx == 0) {
            ps [(size_t)chunk * B_N + rowBlk + r0 + i] = sm[i];
            pmx[(size_t)chunk * B_N + rowBlk + r0 + i] = mx[i];
        }
    }
}

__global__ void classsum_kernel(const float* __restrict__ pmx, const float* __restrict__ ps,
                                const int* __restrict__ labels,
                                float* __restrict__ classSum, unsigned int* __restrict__ classCnt)
{
    __shared__ float        csL[NCLS];
    __shared__ unsigned int ccL[NCLS];
    int t = threadIdx.x;
    if (t < NCLS) { csL[t] = 0.0f; ccL[t] = 0u; }
    __syncthreads();

    int j = blockIdx.x * blockDim.x + t;
    float m = -FLT_MAX, s = 0.0f;
#pragma unroll
    for (int c = 0; c < NCHUNK; ++c) {
        float m2 = pmx[(size_t)c * B_N + j];
        float s2 = ps [(size_t)c * B_N + j];
        float nm = fmaxf(m, m2);
        s = s * __expf(m - nm) + s2 * __expf(m2 - nm);
        m = nm;
    }
    int lab = labels[j];
    atomicAdd(&csL[lab], s);
    atomicAdd(&ccL[lab], 1u);
    __syncthreads();
    if (t < NCLS) {
        atomicAdd(&classSum[t], csL[t]);
        atomicAdd(&classCnt[t], ccL[t]);
    }
}

__global__ void loss_kernel(const float* __restrict__ classSum,
                            const unsigned int* __restrict__ classCnt,
                            float* __restrict__ out)
{
    int c = threadIdx.x;  // 64 threads = 1 wave
    float cs        = (c < NCLS) ? classSum[c] : 0.0f;
    unsigned int cc = (c < NCLS) ? classCnt[c] : 0u;

    float tot = cs;
#pragma unroll
    for (int off = 1; off < 64; off <<= 1) tot += __shfl_xor(tot, off);

    float contrib = 0.0f;
    if (c < NCLS && cc > 0u) {
        float negc = (float)(B_N - (int)cc);
        float nds  = tot - cs;
        float x    = (negc > 0.0f) ? (nds / negc) : nds;
        float lp   = (cc >= 2u) ? (-logf(x + 1e-12f)) : 0.0f;  // mask_sum = cc-1 > 0
        contrib = (float)cc * lp;
    }
#pragma unroll
    for (int off = 1; off < 64; off <<= 1) contrib += __shfl_xor(contrib, off);
    if (c == 0) out[0] = -(contrib / (float)B_N);
}

extern "C" void kernel_launch(void* const* d_in, const int* in_sizes, int n_in,
                              void* d_out, int out_size, void* d_ws, size_t ws_size,
                              hipStream_t stream)
{
    const float* anchor = (const float*)d_in[0];
    const float* target = (const float*)d_in[1];
    const int*   labels = (const int*)d_in[2];
    float* out = (float*)d_out;

    char* ws = (char*)d_ws;
    float* ps  = (float*)ws;                                       // NCHUNK*B_N floats
    float* pmx = (float*)(ws + sizeof(float) * NCHUNK * B_N);      // NCHUNK*B_N floats
    float*        classSum = (float*)(ws + 2 * sizeof(float) * NCHUNK * B_N);
    unsigned int* classCnt = (unsigned int*)(ws + 2 * sizeof(float) * NCHUNK * B_N + 256);

    // zero only the class-aggregate region (pmx/ps are fully overwritten each call)
    hipMemsetAsync(classSum, 0, 512, stream);

    dim3 gridA(NCHUNK, B_N / BM);
    rowstats_kernel<<<gridA, 256, 0, stream>>>(anchor, target, labels, pmx, ps);
    classsum_kernel<<<B_N / 256, 256, 0, stream>>>(pmx, ps, labels, classSum, classCnt);
    loss_kernel<<<1, 64, 0, stream>>>(classSum, classCnt, out);
}

// Round 3
// 77.000 us; speedup vs baseline: 4.6018x; 4.6018x over previous
//
#include <hip/hip_runtime.h>
#include <float.h>
#include <math.h>

typedef __attribute__((ext_vector_type(8))) short bf16x8;
typedef __attribute__((ext_vector_type(4))) float f32x4;
typedef unsigned short ushort_t;

constexpr int B_N  = 8192;
constexpr int D_K  = 128;
constexpr int NCLS = 50;
constexpr int NCHUNK = 8;            // column chunks; grid = 64 rowblocks x 8 = 512 blocks
constexpr int BM  = 128;             // rows per block
constexpr int BNT = 128;             // cols per tile
constexpr float C_SCALE = 28.853900817779268f;   // 20 * log2(e): base-2 scaled d
constexpr float SKIP_MARGIN = 30.0f;             // 2^-30 relative -> negligible
constexpr float NEG_LOW  = -1.0e5f;              // running-max init
constexpr float NEG_MASK = -1.0e30f;             // masked-element sentinel

__device__ __forceinline__ float exp2fast(float x) { return __builtin_amdgcn_exp2f(x); }

__device__ __forceinline__ f32x4 mfma16(bf16x8 a, bf16x8 b, f32x4 c) {
    return __builtin_amdgcn_mfma_f32_16x16x32_bf16(a, b, c, 0, 0, 0);
}

__device__ __forceinline__ void async_copy16(void* lds, const void* g) {
    __builtin_amdgcn_global_load_lds((const __attribute__((address_space(1))) unsigned int*)g,
                                     (__attribute__((address_space(3))) unsigned int*)lds,
                                     16, 0, 0);
}

__device__ __forceinline__ ushort_t f2bf(float f) {
    unsigned u = __builtin_bit_cast(unsigned, f);
    unsigned r = (u + 0x7FFFu + ((u >> 16) & 1u)) >> 16;   // RNE
    return (ushort_t)r;
}
__device__ __forceinline__ float bf2f(ushort_t u) {
    return __builtin_bit_cast(float, (unsigned)u << 16);
}

// ---------------- split: f32 -> bf16 hi + bf16 lo planes ----------------
__global__ void split_kernel(const float* __restrict__ x, ushort_t* __restrict__ hi,
                             ushort_t* __restrict__ lo, int n8)
{
    int i = blockIdx.x * blockDim.x + threadIdx.x;
    if (i >= n8) return;
    const f32x4* xp = (const f32x4*)(x + (size_t)i * 8);
    f32x4 v0 = xp[0], v1 = xp[1];
    bf16x8 H, L;
#pragma unroll
    for (int e = 0; e < 4; ++e) {
        float f0 = v0[e], f1 = v1[e];
        ushort_t h0 = f2bf(f0), h1 = f2bf(f1);
        H[e] = (short)h0; H[e + 4] = (short)h1;
        L[e]     = (short)f2bf(f0 - bf2f(h0));
        L[e + 4] = (short)f2bf(f1 - bf2f(h1));
    }
    *(bf16x8*)(hi + (size_t)i * 8) = H;
    *(bf16x8*)(lo + (size_t)i * 8) = L;
}

// ---------------- main: d = A*B^T (bf16 hi/lo 3-product) + masked online max/sum ----------------
// Wave w owns rows [w*32, w*32+32) x ALL 128 cols of each tile -> each row's full
// column set is inside one wave's 16 l15-lanes (shfl-reduce complete, no write race).
__global__ __launch_bounds__(256, 2)
void rowstats_kernel(const ushort_t* __restrict__ aHi, const ushort_t* __restrict__ aLo,
                     const ushort_t* __restrict__ bHi, const ushort_t* __restrict__ bLo,
                     const int* __restrict__ labels,
                     float* __restrict__ pmx, float* __restrict__ ps)
{
    // LDS: 4 planes of [128 rows][64 bf16] = 16 KB each: Ahi, Alo, Bhi, Blo
    __shared__ __align__(16) char smem[65536];

    const int bid    = blockIdx.x;
    const int chunk  = bid & (NCHUNK - 1);        // default round-robin -> XCD-affine
    const int rowblk = bid >> 3;
    const int R0 = rowblk * BM;
    const int C0 = chunk * (B_N / NCHUNK);

    const int tid = threadIdx.x;
    const int wid = tid >> 6;
    const int l   = tid & 63;
    const int l15 = l & 15, l16 = l >> 4;
    const int wrow = wid * 32;

    // ds-read swizzle: LDS[row][slot] holds global k-group (slot ^ (row&7));
    // need group g = ks*4 + l16 of row with row&7 == (l&7)  ->  byte off = ((g^(l&7))<<4)
    const int slot0 = ((l16 ^ (l & 7)) << 4);
    int aRow[2], bRow[8];
#pragma unroll
    for (int mf = 0; mf < 2; ++mf) aRow[mf] = (wrow + mf * 16 + l15) * 128;
#pragma unroll
    for (int nf = 0; nf < 8; ++nf) bRow[nf] = (nf * 16 + l15) * 128;

    // labels for my 8 output rows (row = wrow + mf*16 + l16*4 + r)
    int labA[8];
#pragma unroll
    for (int mf = 0; mf < 2; ++mf)
#pragma unroll
        for (int r = 0; r < 4; ++r)
            labA[mf * 4 + r] = labels[R0 + wrow + mf * 16 + l16 * 4 + r];

    float mx[8], sm[8];
#pragma unroll
    for (int i = 0; i < 8; ++i) { mx[i] = NEG_LOW; sm[i] = 0.0f; }

    // staging: each issue writes 1024B = 8 rows; lane l -> row +(l>>3), kgroup (l&7)^(l>>3)
    const int srow = l >> 3;
    const int sg   = (l & 7) ^ srow;
    const ushort_t* planes[4] = {aHi, aLo, bHi, bLo};

    for (int tile = 0; tile < (B_N / NCHUNK) / BNT; ++tile) {
        const int colB = C0 + tile * BNT;
        f32x4 acc[2][8];
#pragma unroll
        for (int mf = 0; mf < 2; ++mf)
#pragma unroll
            for (int nf = 0; nf < 8; ++nf) acc[mf][nf] = f32x4{0.f, 0.f, 0.f, 0.f};

#pragma unroll
        for (int bk = 0; bk < 2; ++bk) {
            __syncthreads();                       // prior reads of smem done
#pragma unroll
            for (int p = 0; p < 4; ++p) {
                const int rowbase = (p < 2) ? R0 : colB;
                const ushort_t* src = planes[p];
#pragma unroll
                for (int q = 0; q < 4; ++q) {
                    const int ck = q * 4 + wid;    // 0..15 chunk of 8 rows
                    const int grow = rowbase + ck * 8 + srow;
                    const ushort_t* gp = src + (size_t)grow * D_K + bk * 64 + sg * 8;
                    char* lp = smem + p * 16384 + ck * 1024;   // wave-uniform LDS base
                    async_copy16(lp, gp);
                }
            }
            __syncthreads();                       // vmcnt drained by barrier

#pragma unroll
            for (int ks = 0; ks < 2; ++ks) {
                const int ko = slot0 ^ (ks << 6);
                bf16x8 ah[2], al[2], bh[8], bl[8];
#pragma unroll
                for (int mf = 0; mf < 2; ++mf) {
                    ah[mf] = *(const bf16x8*)(smem + 0     + aRow[mf] + ko);
                    al[mf] = *(const bf16x8*)(smem + 16384 + aRow[mf] + ko);
                }
#pragma unroll
                for (int nf = 0; nf < 8; ++nf) {
                    bh[nf] = *(const bf16x8*)(smem + 32768 + bRow[nf] + ko);
                    bl[nf] = *(const bf16x8*)(smem + 49152 + bRow[nf] + ko);
                }
#pragma unroll
                for (int mf = 0; mf < 2; ++mf)
#pragma unroll
                    for (int nf = 0; nf < 8; ++nf) {
                        acc[mf][nf] = mfma16(ah[mf], bh[nf], acc[mf][nf]);
                        acc[mf][nf] = mfma16(ah[mf], bl[nf], acc[mf][nf]);
                        acc[mf][nf] = mfma16(al[mf], bh[nf], acc[mf][nf]);
                    }
            }
        }

        // ---- epilogue: masked online (max,sum) with per-row-group skip vote ----
        int lB[8];
#pragma unroll
        for (int nf = 0; nf < 8; ++nf) lB[nf] = labels[colB + nf * 16 + l15];

#pragma unroll
        for (int mf = 0; mf < 2; ++mf) {
#pragma unroll
            for (int r = 0; r < 4; ++r) {
                const int i = mf * 4 + r;
                float rmxu = acc[mf][0][r];
#pragma unroll
                for (int nf = 1; nf < 8; ++nf) rmxu = fmaxf(rmxu, acc[mf][nf][r]);
                // vote spans only the 4 physical rows sharing (mf,r) -> skips often
                if (!__all(rmxu * C_SCALE < mx[i] - SKIP_MARGIN)) {
                    float v[8];
#pragma unroll
                    for (int nf = 0; nf < 8; ++nf)
                        v[nf] = (lB[nf] != labA[i]) ? acc[mf][nf][r] * C_SCALE : NEG_MASK;
                    float m0 = fmaxf(fmaxf(v[0], v[1]), fmaxf(v[2], v[3]));
                    float m1 = fmaxf(fmaxf(v[4], v[5]), fmaxf(v[6], v[7]));
                    float nm = fmaxf(mx[i], fmaxf(m0, m1));
                    float e = 0.0f;
#pragma unroll
                    for (int nf = 0; nf < 8; ++nf) e += exp2fast(v[nf] - nm);
                    sm[i] = sm[i] * exp2fast(mx[i] - nm) + e;
                    mx[i] = nm;
                }
            }
        }
    }

    // reduce across the 16 l15-lanes (xor of low 4 bits keeps l16 fixed -> same rows)
#pragma unroll
    for (int i = 0; i < 8; ++i) {
#pragma unroll
        for (int off = 1; off < 16; off <<= 1) {
            float m2 = __shfl_xor(mx[i], off);
            float s2 = __shfl_xor(sm[i], off);
            float nm = fmaxf(mx[i], m2);
            sm[i] = sm[i] * exp2fast(mx[i] - nm) + s2 * exp2fast(m2 - nm);
            mx[i] = nm;
        }
    }
    if (l15 == 0) {
#pragma unroll
        for (int mf = 0; mf < 2; ++mf)
#pragma unroll
            for (int r = 0; r < 4; ++r) {
                int row = R0 + wrow + mf * 16 + l16 * 4 + r;
                pmx[chunk * B_N + row] = mx[mf * 4 + r];
                ps [chunk * B_N + row] = sm[mf * 4 + r];
            }
    }
}

// ---------------- per-row chunk combine + class aggregation ----------------
__global__ void classsum_kernel(const float* __restrict__ pmx, const float* __restrict__ ps,
                                const int* __restrict__ labels,
                                float* __restrict__ classSum, unsigned int* __restrict__ classCnt)
{
    __shared__ float        csL[NCLS];
    __shared__ unsigned int ccL[NCLS];
    int t = threadIdx.x;
    if (t < NCLS) { csL[t] = 0.0f; ccL[t] = 0u; }
    __syncthreads();

    int j = blockIdx.x * blockDim.x + t;
    float m = -FLT_MAX, s = 0.0f;
#pragma unroll
    for (int c = 0; c < NCHUNK; ++c) {
        float m2 = pmx[(size_t)c * B_N + j];
        float s2 = ps [(size_t)c * B_N + j];
        float nm = fmaxf(m, m2);
        s = s * exp2fast(m - nm) + s2 * exp2fast(m2 - nm);
        m = nm;
    }
    int lab = labels[j];
    atomicAdd(&csL[lab], s);
    atomicAdd(&ccL[lab], 1u);
    __syncthreads();
    if (t < NCLS) {
        atomicAdd(&classSum[t], csL[t]);
        atomicAdd(&classCnt[t], ccL[t]);
    }
}

__global__ void loss_kernel(const float* __restrict__ classSum,
                            const unsigned int* __restrict__ classCnt,
                            float* __restrict__ out)
{
    int c = threadIdx.x;  // 64 threads = 1 wave
    float cs        = (c < NCLS) ? classSum[c] : 0.0f;
    unsigned int cc = (c < NCLS) ? classCnt[c] : 0u;

    float tot = cs;
#pragma unroll
    for (int off = 1; off < 64; off <<= 1) tot += __shfl_xor(tot, off);

    float contrib = 0.0f;
    if (c < NCLS && cc > 0u) {
        float negc = (float)(B_N - (int)cc);
        float nds  = tot - cs;
        float x    = (negc > 0.0f) ? (nds / negc) : nds;
        float lp   = (cc >= 2u) ? (-logf(x + 1e-12f)) : 0.0f;
        contrib = (float)cc * lp;
    }
#pragma unroll
    for (int off = 1; off < 64; off <<= 1) contrib += __shfl_xor(contrib, off);
    if (c == 0) out[0] = -(contrib / (float)B_N);
}

extern "C" void kernel_launch(void* const* d_in, const int* in_sizes, int n_in,
                              void* d_out, int out_size, void* d_ws, size_t ws_size,
                              hipStream_t stream)
{
    const float* anchor = (const float*)d_in[0];
    const float* target = (const float*)d_in[1];
    const int*   labels = (const int*)d_in[2];
    float* out = (float*)d_out;

    const size_t PLANE = (size_t)B_N * D_K * sizeof(ushort_t);   // 2 MB
    char* ws = (char*)d_ws;
    ushort_t* aHi = (ushort_t*)(ws + 0 * PLANE);
    ushort_t* aLo = (ushort_t*)(ws + 1 * PLANE);
    ushort_t* bHi = (ushort_t*)(ws + 2 * PLANE);
    ushort_t* bLo = (ushort_t*)(ws + 3 * PLANE);
    float* ps  = (float*)(ws + 4 * PLANE);
    float* pmx = (float*)(ws + 4 * PLANE + sizeof(float) * NCHUNK * B_N);
    char*  cls = ws + 4 * PLANE + 2 * sizeof(float) * NCHUNK * B_N;
    float*        classSum = (float*)cls;
    unsigned int* classCnt = (unsigned int*)(cls + 256);

    hipMemsetAsync(classSum, 0, 512, stream);

    const int n8 = B_N * D_K / 8;   // 131072 groups of 8
    split_kernel<<<n8 / 256, 256, 0, stream>>>(anchor, aHi, aLo, n8);
    split_kernel<<<n8 / 256, 256, 0, stream>>>(target, bHi, bLo, n8);

    rowstats_kernel<<<64 * NCHUNK, 256, 0, stream>>>(aHi, aLo, bHi, bLo, labels, pmx, ps);
    classsum_kernel<<<B_N / 256, 256, 0, stream>>>(pmx, ps, labels, classSum, classCnt);
    loss_kernel<<<1, 64, 0, stream>>>(classSum, classCnt, out);
}

// Round 4
// 60.779 us; speedup vs baseline: 5.8299x; 1.2669x over previous
//
#include <hip/hip_runtime.h>
#include <float.h>
#include <math.h>

typedef __attribute__((ext_vector_type(8))) short short8;
typedef __attribute__((ext_vector_type(8))) _Float16 half8;
typedef __attribute__((ext_vector_type(4))) float f32x4;

constexpr int B_N  = 8192;
constexpr int D_KK = 128;
constexpr int NCLS = 50;
constexpr int NCHUNK = 8;              // 1024 cols per chunk
constexpr int BLK_ROWS = 256;          // rows per block (8 waves x 64 rows / 2 col-groups)
constexpr int TCOLS = 128;             // cols per tile
constexpr float C_SCALE   = 28.853900817779268f;   // 20*log2(e): base-2 scale of d
constexpr float MARGIN_DOT = 40.0f / 28.853900817779268f;  // skip margin in dot units
constexpr float NEG_LOW  = -1.0e5f;
constexpr float NEG_MASK = -1.0e30f;

__device__ __forceinline__ float exp2fast(float x) { return __builtin_amdgcn_exp2f(x); }

__device__ __forceinline__ void async_copy16(void* lds, const void* g) {
    __builtin_amdgcn_global_load_lds((const __attribute__((address_space(1))) unsigned int*)g,
                                     (__attribute__((address_space(3))) unsigned int*)lds,
                                     16, 0, 0);
}

// ---------------- f32 -> f16 conversion (both tensors, one kernel) ----------------
__global__ void tof16_kernel(const float* __restrict__ a, const float* __restrict__ b,
                             short* __restrict__ aH, short* __restrict__ bH)
{
    const int NPER = B_N * D_KK / 8;                  // 131072 groups of 8
    int i = blockIdx.x * blockDim.x + threadIdx.x;    // 0..262143
    const float* src = (i < NPER) ? a : b;
    short*       dst = (i < NPER) ? aH : bH;
    int j = (i < NPER) ? i : i - NPER;
    const f32x4* sp = (const f32x4*)(src + (size_t)j * 8);
    f32x4 v0 = sp[0], v1 = sp[1];
    short8 h;
#pragma unroll
    for (int e = 0; e < 4; ++e) {
        h[e]     = __builtin_bit_cast(short, (_Float16)v0[e]);
        h[e + 4] = __builtin_bit_cast(short, (_Float16)v1[e]);
    }
    *(short8*)(dst + (size_t)j * 8) = h;
}

// ---------------- main: d = A*B^T (f16 single product) + masked online max/sum ----------------
// 8 waves: wr = wid>>1 (4 row-groups of 64 rows), wc = wid&1 (2 col-groups of 64 cols).
// A-fragments held in registers for the whole block (zero LDS traffic for A).
// B double-buffered in LDS, 2-phase schedule, XOR-swizzled for conflict-free ds_read_b128.
__global__ __launch_bounds__(512, 2)
void rowstats_kernel(const short* __restrict__ aH, const short* __restrict__ bH,
                     const int* __restrict__ labels,
                     float* __restrict__ pmx, float* __restrict__ ps)
{
    __shared__ __align__(16) char bbuf[2][TCOLS * 256];     // 2 x 32 KB
    __shared__ float mergebuf[BLK_ROWS][2];

    const int bid   = blockIdx.x;
    const int chunk = bid & (NCHUNK - 1);                   // XCD-affine
    const int R0 = (bid >> 3) * BLK_ROWS;
    const int C0 = chunk * (B_N / NCHUNK);

    const int tid = threadIdx.x;
    const int wid = tid >> 6, l = tid & 63;
    const int l15 = l & 15, l16 = l >> 4;
    const int wr = wid >> 1, wc = wid & 1;

    // ---- A fragments -> registers: wave's 64 rows x 128 K ----
    half8 aF[4][4];                                         // [mf][ks]
#pragma unroll
    for (int mf = 0; mf < 4; ++mf) {
        const int arow = R0 + wr * 64 + mf * 16 + l15;
#pragma unroll
        for (int ks = 0; ks < 4; ++ks)
            aF[mf][ks] = __builtin_bit_cast(half8,
                *(const short8*)(aH + (size_t)arow * D_KK + ks * 32 + l16 * 8));
    }

    int labA[16];
#pragma unroll
    for (int mf = 0; mf < 4; ++mf)
#pragma unroll
        for (int r = 0; r < 4; ++r)
            labA[mf * 4 + r] = labels[R0 + wr * 64 + mf * 16 + l16 * 4 + r];

    float mx[16], sm[16];
#pragma unroll
    for (int i = 0; i < 16; ++i) { mx[i] = NEG_LOW; sm[i] = 0.0f; }

    // staging: LDS linear (col, slot') receives global slot = slot' ^ (col&7)
    const int scol = tid >> 4;          // 0..31 (+32 per issue)
    const int slotp = tid & 15;

    const int NT = (B_N / NCHUNK) / TCOLS;   // 8 tiles

#define STAGE(tile, bsel)                                                            \
    {                                                                                \
        _Pragma("unroll")                                                            \
        for (int q = 0; q < 4; ++q) {                                                \
            int col = q * 32 + scol;                                                 \
            int gslot = slotp ^ (col & 7);                                           \
            const short* gp = bH + (size_t)(C0 + (tile) * TCOLS + col) * D_KK + gslot * 8; \
            char* lp = &bbuf[bsel][q * 8192 + tid * 16];                             \
            async_copy16(lp, gp);                                                    \
        }                                                                            \
    }

    STAGE(0, 0);
    __syncthreads();

    for (int t = 0; t < NT; ++t) {
        const int cur = t & 1;
        if (t + 1 < NT) STAGE(t + 1, cur ^ 1);

        f32x4 acc[4][4];
#pragma unroll
        for (int mf = 0; mf < 4; ++mf)
#pragma unroll
            for (int nf = 0; nf < 4; ++nf) acc[mf][nf] = f32x4{0.f, 0.f, 0.f, 0.f};

#pragma unroll
        for (int ks = 0; ks < 4; ++ks) {
            half8 bF[4];
#pragma unroll
            for (int nf = 0; nf < 4; ++nf) {
                int col  = wc * 64 + nf * 16 + l15;
                int slot = (ks * 4 + l16) ^ (col & 7);
                bF[nf] = __builtin_bit_cast(half8,
                    *(const short8*)(&bbuf[cur][col * 256 + slot * 16]));
            }
#pragma unroll
            for (int mf = 0; mf < 4; ++mf)
#pragma unroll
                for (int nf = 0; nf < 4; ++nf)
                    acc[mf][nf] = __builtin_amdgcn_mfma_f32_16x16x32_f16(
                        aF[mf][ks], bF[nf], acc[mf][nf], 0, 0, 0);
        }

        // ---- epilogue: masked online (max,sum) in raw-dot units, skip vote per mf ----
        const int colB = C0 + t * TCOLS;
        int lB[4];
#pragma unroll
        for (int nf = 0; nf < 4; ++nf) lB[nf] = labels[colB + wc * 64 + nf * 16 + l15];

#pragma unroll
        for (int mf = 0; mf < 4; ++mf) {
            float gm = acc[mf][0][0];
#pragma unroll
            for (int nf = 0; nf < 4; ++nf)
#pragma unroll
                for (int r = 0; r < 4; ++r) gm = fmaxf(gm, acc[mf][nf][r]);
            int sk = 1;
#pragma unroll
            for (int r = 0; r < 4; ++r) sk &= (gm < mx[mf * 4 + r] - MARGIN_DOT) ? 1 : 0;
            if (!__all(sk)) {
#pragma unroll
                for (int r = 0; r < 4; ++r) {
                    const int i = mf * 4 + r;
                    float v0 = (lB[0] != labA[i]) ? acc[mf][0][r] : NEG_MASK;
                    float v1 = (lB[1] != labA[i]) ? acc[mf][1][r] : NEG_MASK;
                    float v2 = (lB[2] != labA[i]) ? acc[mf][2][r] : NEG_MASK;
                    float v3 = (lB[3] != labA[i]) ? acc[mf][3][r] : NEG_MASK;
                    float nm = fmaxf(mx[i], fmaxf(fmaxf(v0, v1), fmaxf(v2, v3)));
                    float e = exp2fast(C_SCALE * (v0 - nm)) + exp2fast(C_SCALE * (v1 - nm))
                            + exp2fast(C_SCALE * (v2 - nm)) + exp2fast(C_SCALE * (v3 - nm));
                    sm[i] = sm[i] * exp2fast(C_SCALE * (mx[i] - nm)) + e;
                    mx[i] = nm;
                }
            }
        }
        __syncthreads();   // staged t+1 landed (vmcnt drained) + all reads of cur done
    }

    // ---- intra-wave reduce across 16 column-lanes ----
#pragma unroll
    for (int i = 0; i < 16; ++i) {
#pragma unroll
        for (int off = 1; off < 16; off <<= 1) {
            float m2 = __shfl_xor(mx[i], off);
            float s2 = __shfl_xor(sm[i], off);
            float nm = fmaxf(mx[i], m2);
            sm[i] = sm[i] * exp2fast(C_SCALE * (mx[i] - nm))
                  + s2   * exp2fast(C_SCALE * (m2 - nm));
            mx[i] = nm;
        }
    }

    // ---- cross-wave (wc) merge via LDS, then write ----
    if (wc == 1 && l15 == 0) {
#pragma unroll
        for (int mf = 0; mf < 4; ++mf)
#pragma unroll
            for (int r = 0; r < 4; ++r) {
                int rl = wr * 64 + mf * 16 + l16 * 4 + r;
                mergebuf[rl][0] = mx[mf * 4 + r];
                mergebuf[rl][1] = sm[mf * 4 + r];
            }
    }
    __syncthreads();
    if (wc == 0 && l15 == 0) {
#pragma unroll
        for (int mf = 0; mf < 4; ++mf)
#pragma unroll
            for (int r = 0; r < 4; ++r) {
                const int i = mf * 4 + r;
                int rl = wr * 64 + mf * 16 + l16 * 4 + r;
                float m2 = mergebuf[rl][0], s2 = mergebuf[rl][1];
                float nm = fmaxf(mx[i], m2);
                float s  = sm[i] * exp2fast(C_SCALE * (mx[i] - nm))
                         + s2   * exp2fast(C_SCALE * (m2 - nm));
                pmx[chunk * B_N + R0 + rl] = nm * C_SCALE;   // store in base-2 units
                ps [chunk * B_N + R0 + rl] = s;
            }
    }
#undef STAGE
}

// ---------------- per-row chunk combine + class aggregation ----------------
__global__ void classsum_kernel(const float* __restrict__ pmx, const float* __restrict__ ps,
                                const int* __restrict__ labels,
                                float* __restrict__ classSum, unsigned int* __restrict__ classCnt)
{
    __shared__ float        csL[NCLS];
    __shared__ unsigned int ccL[NCLS];
    int t = threadIdx.x;
    if (t < NCLS) { csL[t] = 0.0f; ccL[t] = 0u; }
    __syncthreads();

    int j = blockIdx.x * blockDim.x + t;
    float m = -FLT_MAX, s = 0.0f;
#pragma unroll
    for (int c = 0; c < NCHUNK; ++c) {
        float m2 = pmx[(size_t)c * B_N + j];
        float s2 = ps [(size_t)c * B_N + j];
        float nm = fmaxf(m, m2);
        s = s * exp2fast(m - nm) + s2 * exp2fast(m2 - nm);
        m = nm;
    }
    int lab = labels[j];
    atomicAdd(&csL[lab], s);
    atomicAdd(&ccL[lab], 1u);
    __syncthreads();
    if (t < NCLS) {
        atomicAdd(&classSum[t], csL[t]);
        atomicAdd(&classCnt[t], ccL[t]);
    }
}

__global__ void loss_kernel(const float* __restrict__ classSum,
                            const unsigned int* __restrict__ classCnt,
                            float* __restrict__ out)
{
    int c = threadIdx.x;  // 64 threads = 1 wave
    float cs        = (c < NCLS) ? classSum[c] : 0.0f;
    unsigned int cc = (c < NCLS) ? classCnt[c] : 0u;

    float tot = cs;
#pragma unroll
    for (int off = 1; off < 64; off <<= 1) tot += __shfl_xor(tot, off);

    float contrib = 0.0f;
    if (c < NCLS && cc > 0u) {
        float negc = (float)(B_N - (int)cc);
        float nds  = tot - cs;
        float x    = (negc > 0.0f) ? (nds / negc) : nds;
        float lp   = (cc >= 2u) ? (-logf(x + 1e-12f)) : 0.0f;
        contrib = (float)cc * lp;
    }
#pragma unroll
    for (int off = 1; off < 64; off <<= 1) contrib += __shfl_xor(contrib, off);
    if (c == 0) out[0] = -(contrib / (float)B_N);
}

extern "C" void kernel_launch(void* const* d_in, const int* in_sizes, int n_in,
                              void* d_out, int out_size, void* d_ws, size_t ws_size,
                              hipStream_t stream)
{
    const float* anchor = (const float*)d_in[0];
    const float* target = (const float*)d_in[1];
    const int*   labels = (const int*)d_in[2];
    float* out = (float*)d_out;

    const size_t PLANE = (size_t)B_N * D_KK * sizeof(short);   // 2 MB
    char* ws = (char*)d_ws;
    short* aH = (short*)(ws + 0 * PLANE);
    short* bH = (short*)(ws + 1 * PLANE);
    float* ps  = (float*)(ws + 2 * PLANE);
    float* pmx = (float*)(ws + 2 * PLANE + sizeof(float) * NCHUNK * B_N);
    char*  cls = ws + 2 * PLANE + 2 * sizeof(float) * NCHUNK * B_N;
    float*        classSum = (float*)cls;
    unsigned int* classCnt = (unsigned int*)(cls + 256);

    hipMemsetAsync(classSum, 0, 512, stream);

    tof16_kernel<<<2 * (B_N * D_KK / 8) / 256, 256, 0, stream>>>(anchor, target, aH, bH);
    rowstats_kernel<<<(B_N / BLK_ROWS) * NCHUNK, 512, 0, stream>>>(aH, bH, labels, pmx, ps);
    classsum_kernel<<<B_N / 256, 256, 0, stream>>>(pmx, ps, labels, classSum, classCnt);
    loss_kernel<<<1, 64, 0, stream>>>(classSum, classCnt, out);
}

// Round 5
// 57.359 us; speedup vs baseline: 6.1776x; 1.0596x over previous
//
#include <hip/hip_runtime.h>
#include <float.h>
#include <math.h>

typedef __attribute__((ext_vector_type(8))) short short8;
typedef __attribute__((ext_vector_type(8))) _Float16 half8;
typedef __attribute__((ext_vector_type(4))) float f32x4;

constexpr int B_N  = 8192;
constexpr int D_KK = 128;
constexpr int NCLS = 50;
constexpr int NCHUNK = 8;              // 1024 cols per chunk
constexpr int BLK_ROWS = 64;           // rows per block (2 wr x 32 rows)
constexpr int TCOLS = 64;              // cols per tile
constexpr float C_SCALE = 28.853900817779268f;   // 20*log2(e), folded into A at conversion
constexpr float MARGIN  = 40.0f;                 // skip margin, base-2 units
constexpr float NEG_LOW  = -1.0e5f;
constexpr float NEG_MASK = -1.0e30f;

__device__ __forceinline__ float exp2fast(float x) { return __builtin_amdgcn_exp2f(x); }

__device__ __forceinline__ void async_copy16(void* lds, const void* g) {
    __builtin_amdgcn_global_load_lds((const __attribute__((address_space(1))) unsigned int*)g,
                                     (__attribute__((address_space(3))) unsigned int*)lds,
                                     16, 0, 0);
}

// ---------------- f32 -> f16 (anchor pre-scaled by C_SCALE) ----------------
__global__ void tof16_kernel(const float* __restrict__ a, const float* __restrict__ b,
                             short* __restrict__ aH, short* __restrict__ bH)
{
    const int NPER = B_N * D_KK / 8;                  // 131072 groups of 8
    int i = blockIdx.x * blockDim.x + threadIdx.x;    // 0..262143
    const float* src = (i < NPER) ? a : b;
    short*       dst = (i < NPER) ? aH : bH;
    const float  sc  = (i < NPER) ? C_SCALE : 1.0f;
    int j = (i < NPER) ? i : i - NPER;
    const f32x4* sp = (const f32x4*)(src + (size_t)j * 8);
    f32x4 v0 = sp[0], v1 = sp[1];
    short8 h;
#pragma unroll
    for (int e = 0; e < 4; ++e) {
        h[e]     = __builtin_bit_cast(short, (_Float16)(sc * v0[e]));
        h[e + 4] = __builtin_bit_cast(short, (_Float16)(sc * v1[e]));
    }
    *(short8*)(dst + (size_t)j * 8) = h;
}

// ---------------- main: d(base-2) = (C*A)*B^T f16 + masked online max/sum ----------------
// 256-thread blocks, 4 waves: wr = wid>>1 (2 x 32 rows), wc = wid&1 (2 x 32 cols).
// A in registers; B double-buffered in LDS (XOR-swizzled), 2-phase schedule.
// 4 blocks/CU (33 KB LDS, <=128 VGPR) -> 16 waves/CU for latency hiding.
__global__ __launch_bounds__(256, 4)
void rowstats_kernel(const short* __restrict__ aH, const short* __restrict__ bH,
                     const int* __restrict__ labels,
                     float* __restrict__ pmx, float* __restrict__ ps)
{
    __shared__ __align__(16) char bbuf[2][TCOLS * 256];     // 2 x 16 KB
    __shared__ float mergebuf[BLK_ROWS][2];

    const int bid   = blockIdx.x;
    const int chunk = bid & (NCHUNK - 1);                   // XCD-affine
    const int R0 = (bid >> 3) * BLK_ROWS;
    const int C0 = chunk * (B_N / NCHUNK);

    const int tid = threadIdx.x;
    const int wid = tid >> 6, l = tid & 63;
    const int l15 = l & 15, l16 = l >> 4;
    const int wr = wid >> 1, wc = wid & 1;

    // ---- A fragments -> registers: wave's 32 rows x 128 K ----
    half8 aF[2][4];                                         // [mf][ks]
#pragma unroll
    for (int mf = 0; mf < 2; ++mf) {
        const int arow = R0 + wr * 32 + mf * 16 + l15;
#pragma unroll
        for (int ks = 0; ks < 4; ++ks)
            aF[mf][ks] = __builtin_bit_cast(half8,
                *(const short8*)(aH + (size_t)arow * D_KK + ks * 32 + l16 * 8));
    }

    int labA[8];
#pragma unroll
    for (int mf = 0; mf < 2; ++mf)
#pragma unroll
        for (int r = 0; r < 4; ++r)
            labA[mf * 4 + r] = labels[R0 + wr * 32 + mf * 16 + l16 * 4 + r];

    float mx[8], sm[8];
#pragma unroll
    for (int i = 0; i < 8; ++i) { mx[i] = NEG_LOW; sm[i] = 0.0f; }

    const int NT = (B_N / NCHUNK) / TCOLS;   // 16 tiles

#define STAGE(tile, bsel)                                                            \
    {                                                                                \
        _Pragma("unroll")                                                            \
        for (int q = 0; q < 4; ++q) {                                                \
            int col = q * 16 + (tid >> 4);                                           \
            int gslot = (tid & 15) ^ (col & 7);                                      \
            const short* gp = bH + (size_t)(C0 + (tile) * TCOLS + col) * D_KK + gslot * 8; \
            char* lp = &bbuf[bsel][q * 4096 + tid * 16];                             \
            async_copy16(lp, gp);                                                    \
        }                                                                            \
    }

    STAGE(0, 0);
    __syncthreads();

    for (int t = 0; t < NT; ++t) {
        const int cur = t & 1;
        if (t + 1 < NT) STAGE(t + 1, cur ^ 1);

        f32x4 acc[2][2];
#pragma unroll
        for (int mf = 0; mf < 2; ++mf)
#pragma unroll
            for (int nf = 0; nf < 2; ++nf) acc[mf][nf] = f32x4{0.f, 0.f, 0.f, 0.f};

#pragma unroll
        for (int ks = 0; ks < 4; ++ks) {
            half8 bF[2];
#pragma unroll
            for (int nf = 0; nf < 2; ++nf) {
                int col  = wc * 32 + nf * 16 + l15;
                int slot = (ks * 4 + l16) ^ (col & 7);
                bF[nf] = __builtin_bit_cast(half8,
                    *(const short8*)(&bbuf[cur][col * 256 + slot * 16]));
            }
#pragma unroll
            for (int mf = 0; mf < 2; ++mf)
#pragma unroll
                for (int nf = 0; nf < 2; ++nf)
                    acc[mf][nf] = __builtin_amdgcn_mfma_f32_16x16x32_f16(
                        aF[mf][ks], bF[nf], acc[mf][nf], 0, 0, 0);
        }

        // ---- epilogue: masked online (max,sum), base-2 units, skip vote per mf ----
        const int colB = C0 + t * TCOLS;
        int lB[2];
#pragma unroll
        for (int nf = 0; nf < 2; ++nf) lB[nf] = labels[colB + wc * 32 + nf * 16 + l15];

#pragma unroll
        for (int mf = 0; mf < 2; ++mf) {
            float gm = fmaxf(fmaxf(fmaxf(acc[mf][0][0], acc[mf][0][1]),
                                   fmaxf(acc[mf][0][2], acc[mf][0][3])),
                             fmaxf(fmaxf(acc[mf][1][0], acc[mf][1][1]),
                                   fmaxf(acc[mf][1][2], acc[mf][1][3])));
            int sk = 1;
#pragma unroll
            for (int r = 0; r < 4; ++r) sk &= (gm < mx[mf * 4 + r] - MARGIN) ? 1 : 0;
            if (!__all(sk)) {
#pragma unroll
                for (int r = 0; r < 4; ++r) {
                    const int i = mf * 4 + r;
                    float v0 = (lB[0] != labA[i]) ? acc[mf][0][r] : NEG_MASK;
                    float v1 = (lB[1] != labA[i]) ? acc[mf][1][r] : NEG_MASK;
                    float nm = fmaxf(mx[i], fmaxf(v0, v1));
                    float e  = exp2fast(v0 - nm) + exp2fast(v1 - nm);
                    sm[i] = sm[i] * exp2fast(mx[i] - nm) + e;
                    mx[i] = nm;
                }
            }
        }
        __syncthreads();   // staged t+1 landed + all reads of cur done
    }

    // ---- intra-wave reduce across 16 column-lanes ----
#pragma unroll
    for (int i = 0; i < 8; ++i) {
#pragma unroll
        for (int off = 1; off < 16; off <<= 1) {
            float m2 = __shfl_xor(mx[i], off);
            float s2 = __shfl_xor(sm[i], off);
            float nm = fmaxf(mx[i], m2);
            sm[i] = sm[i] * exp2fast(mx[i] - nm) + s2 * exp2fast(m2 - nm);
            mx[i] = nm;
        }
    }

    // ---- cross-wave (wc) merge via LDS, then write ----
    if (wc == 1 && l15 == 0) {
#pragma unroll
        for (int mf = 0; mf < 2; ++mf)
#pragma unroll
            for (int r = 0; r < 4; ++r) {
                int rl = wr * 32 + mf * 16 + l16 * 4 + r;
                mergebuf[rl][0] = mx[mf * 4 + r];
                mergebuf[rl][1] = sm[mf * 4 + r];
            }
    }
    __syncthreads();
    if (wc == 0 && l15 == 0) {
#pragma unroll
        for (int mf = 0; mf < 2; ++mf)
#pragma unroll
            for (int r = 0; r < 4; ++r) {
                const int i = mf * 4 + r;
                int rl = wr * 32 + mf * 16 + l16 * 4 + r;
                float m2 = mergebuf[rl][0], s2 = mergebuf[rl][1];
                float nm = fmaxf(mx[i], m2);
                float s  = sm[i] * exp2fast(mx[i] - nm) + s2 * exp2fast(m2 - nm);
                pmx[chunk * B_N + R0 + rl] = nm;     // already base-2 units
                ps [chunk * B_N + R0 + rl] = s;
            }
    }
#undef STAGE
}

// ---------------- per-row chunk combine + class aggregation ----------------
__global__ void classsum_kernel(const float* __restrict__ pmx, const float* __restrict__ ps,
                                const int* __restrict__ labels,
                                float* __restrict__ classSum, unsigned int* __restrict__ classCnt)
{
    __shared__ float        csL[NCLS];
    __shared__ unsigned int ccL[NCLS];
    int t = threadIdx.x;
    if (t < NCLS) { csL[t] = 0.0f; ccL[t] = 0u; }
    __syncthreads();

    int j = blockIdx.x * blockDim.x + t;
    float m = -FLT_MAX, s = 0.0f;
#pragma unroll
    for (int c = 0; c < NCHUNK; ++c) {
        float m2 = pmx[(size_t)c * B_N + j];
        float s2 = ps [(size_t)c * B_N + j];
        float nm = fmaxf(m, m2);
        s = s * exp2fast(m - nm) + s2 * exp2fast(m2 - nm);
        m = nm;
    }
    int lab = labels[j];
    atomicAdd(&csL[lab], s);
    atomicAdd(&ccL[lab], 1u);
    __syncthreads();
    if (t < NCLS) {
        atomicAdd(&classSum[t], csL[t]);
        atomicAdd(&classCnt[t], ccL[t]);
    }
}

__global__ void loss_kernel(const float* __restrict__ classSum,
                            const unsigned int* __restrict__ classCnt,
                            float* __restrict__ out)
{
    int c = threadIdx.x;  // 64 threads = 1 wave
    float cs        = (c < NCLS) ? classSum[c] : 0.0f;
    unsigned int cc = (c < NCLS) ? classCnt[c] : 0u;

    float tot = cs;
#pragma unroll
    for (int off = 1; off < 64; off <<= 1) tot += __shfl_xor(tot, off);

    float contrib = 0.0f;
    if (c < NCLS && cc > 0u) {
        float negc = (float)(B_N - (int)cc);
        float nds  = tot - cs;
        float x    = (negc > 0.0f) ? (nds / negc) : nds;
        float lp   = (cc >= 2u) ? (-logf(x + 1e-12f)) : 0.0f;
        contrib = (float)cc * lp;
    }
#pragma unroll
    for (int off = 1; off < 64; off <<= 1) contrib += __shfl_xor(contrib, off);
    if (c == 0) out[0] = -(contrib / (float)B_N);
}

extern "C" void kernel_launch(void* const* d_in, const int* in_sizes, int n_in,
                              void* d_out, int out_size, void* d_ws, size_t ws_size,
                              hipStream_t stream)
{
    const float* anchor = (const float*)d_in[0];
    const float* target = (const float*)d_in[1];
    const int*   labels = (const int*)d_in[2];
    float* out = (float*)d_out;

    const size_t PLANE = (size_t)B_N * D_KK * sizeof(short);   // 2 MB
    char* ws = (char*)d_ws;
    short* aH = (short*)(ws + 0 * PLANE);
    short* bH = (short*)(ws + 1 * PLANE);
    float* ps  = (float*)(ws + 2 * PLANE);
    float* pmx = (float*)(ws + 2 * PLANE + sizeof(float) * NCHUNK * B_N);
    char*  cls = ws + 2 * PLANE + 2 * sizeof(float) * NCHUNK * B_N;
    float*        classSum = (float*)cls;
    unsigned int* classCnt = (unsigned int*)(cls + 256);

    hipMemsetAsync(classSum, 0, 512, stream);

    tof16_kernel<<<2 * (B_N * D_KK / 8) / 256, 256, 0, stream>>>(anchor, target, aH, bH);
    rowstats_kernel<<<(B_N / BLK_ROWS) * NCHUNK, 256, 0, stream>>>(aH, bH, labels, pmx, ps);
    classsum_kernel<<<B_N / 256, 256, 0, stream>>>(pmx, ps, labels, classSum, classCnt);
    loss_kernel<<<1, 64, 0, stream>>>(classSum, classCnt, out);
}

// Round 6
// 55.148 us; speedup vs baseline: 6.4253x; 1.0401x over previous
//
#include <hip/hip_runtime.h>
#include <float.h>
#include <math.h>

typedef __attribute__((ext_vector_type(8))) short short8;
typedef __attribute__((ext_vector_type(8))) _Float16 half8;
typedef __attribute__((ext_vector_type(4))) float f32x4;

constexpr int B_N  = 8192;
constexpr int D_KK = 128;
constexpr int NCLS = 50;
constexpr int NCHUNK = 16;             // 512 cols per chunk; chunk = bid&15 -> XCD-affine
constexpr int CCOLS = B_N / NCHUNK;    // 512
constexpr float C_SCALE = 28.853900817779268f;   // 20*log2(e), folded into A at conversion
constexpr float MARGIN  = 40.0f;                 // skip margin, base-2 units
constexpr float NEG_LOW  = -1.0e5f;
constexpr float NEG_MASK = -1.0e30f;

__device__ __forceinline__ float exp2fast(float x) { return __builtin_amdgcn_exp2f(x); }

// ---------------- prep: A -> f16 row-major (pre-scaled); B -> f16 k-major transpose ----------------
// bT layout: [kq 0..15][col 0..8191][e 0..7]  (kq = k/8)
__global__ void prep_kernel(const float* __restrict__ a, const float* __restrict__ b,
                            short* __restrict__ aH, short* __restrict__ bT)
{
    const int NPER = B_N * D_KK / 8;                  // 131072
    int i = blockIdx.x * blockDim.x + threadIdx.x;    // 0..262143
    if (i < NPER) {
        // A path: 8 consecutive f32 -> short8, scaled by C_SCALE
        const f32x4* sp = (const f32x4*)(a + (size_t)i * 8);
        f32x4 v0 = sp[0], v1 = sp[1];
        short8 h;
#pragma unroll
        for (int e = 0; e < 4; ++e) {
            h[e]     = __builtin_bit_cast(short, (_Float16)(C_SCALE * v0[e]));
            h[e + 4] = __builtin_bit_cast(short, (_Float16)(C_SCALE * v1[e]));
        }
        *(short8*)(aH + (size_t)i * 8) = h;
    } else {
        // B path: j = kq*? -> coalesced reads: consecutive threads cover kq fastest
        int j   = i - NPER;          // 0..131071
        int kq  = j & 15;            // k-group
        int col = j >> 4;            // 0..8191
        const f32x4* sp = (const f32x4*)(b + (size_t)col * D_KK + kq * 8);
        f32x4 v0 = sp[0], v1 = sp[1];
        short8 h;
#pragma unroll
        for (int e = 0; e < 4; ++e) {
            h[e]     = __builtin_bit_cast(short, (_Float16)v0[e]);
            h[e + 4] = __builtin_bit_cast(short, (_Float16)v1[e]);
        }
        *(short8*)(bT + (size_t)kq * B_N * 8 + (size_t)col * 8) = h;
    }
}

// ---------------- main: no LDS, no barriers. Each wave: 32 rows x 512 cols sweep ----------------
// Block = 4 waves = 4 row-groups of 32 rows (128 rows/block), all sharing the chunk's columns.
// B fragments loaded straight from L1/L2 (bT k-major -> 256B-contiguous per 16-lane group).
__global__ __launch_bounds__(256, 4)
void rowstats_kernel(const short* __restrict__ aH, const short* __restrict__ bT,
                     const int* __restrict__ labels,
                     float* __restrict__ pmx, float* __restrict__ ps)
{
    const int bid   = blockIdx.x;
    const int chunk = bid & (NCHUNK - 1);
    const int R0    = (bid >> 4) * 128;
    const int C0    = chunk * CCOLS;

    const int tid = threadIdx.x;
    const int wid = tid >> 6, l = tid & 63;
    const int l15 = l & 15, l16 = l >> 4;
    const int wrow = R0 + wid * 32;

    // ---- A fragments -> registers: wave's 32 rows x 128 K ----
    half8 aF[2][4];                                         // [mf][ks]
#pragma unroll
    for (int mf = 0; mf < 2; ++mf) {
        const int arow = wrow + mf * 16 + l15;
#pragma unroll
        for (int ks = 0; ks < 4; ++ks)
            aF[mf][ks] = __builtin_bit_cast(half8,
                *(const short8*)(aH + (size_t)arow * D_KK + ks * 32 + l16 * 8));
    }

    int labA[8];
#pragma unroll
    for (int mf = 0; mf < 2; ++mf)
#pragma unroll
        for (int r = 0; r < 4; ++r)
            labA[mf * 4 + r] = labels[wrow + mf * 16 + l16 * 4 + r];

    float mx[8], sm[8];
#pragma unroll
    for (int i = 0; i < 8; ++i) { mx[i] = NEG_LOW; sm[i] = 0.0f; }

    // per-lane B fragment base pointers: [nf][ks], advance 32 cols (=256 shorts) per tile
    const short* bBase[2][4];
#pragma unroll
    for (int nf = 0; nf < 2; ++nf)
#pragma unroll
        for (int ks = 0; ks < 4; ++ks)
            bBase[nf][ks] = bT + (size_t)(ks * 4 + l16) * B_N * 8
                               + (size_t)(C0 + nf * 16 + l15) * 8;

    const int NT = CCOLS / 32;   // 16 tiles of 32 cols

#pragma unroll 2
    for (int t = 0; t < NT; ++t) {
        half8 bF[2][4];
#pragma unroll
        for (int nf = 0; nf < 2; ++nf)
#pragma unroll
            for (int ks = 0; ks < 4; ++ks)
                bF[nf][ks] = __builtin_bit_cast(half8,
                    *(const short8*)(bBase[nf][ks] + t * 256));

        f32x4 acc[2][2];
#pragma unroll
        for (int mf = 0; mf < 2; ++mf)
#pragma unroll
            for (int nf = 0; nf < 2; ++nf) acc[mf][nf] = f32x4{0.f, 0.f, 0.f, 0.f};

#pragma unroll
        for (int ks = 0; ks < 4; ++ks)
#pragma unroll
            for (int mf = 0; mf < 2; ++mf)
#pragma unroll
                for (int nf = 0; nf < 2; ++nf)
                    acc[mf][nf] = __builtin_amdgcn_mfma_f32_16x16x32_f16(
                        aF[mf][ks], bF[nf][ks], acc[mf][nf], 0, 0, 0);

        // ---- epilogue: masked online (max,sum), base-2 units, skip vote per mf ----
        const int colB = C0 + t * 32;
        int lB[2];
#pragma unroll
        for (int nf = 0; nf < 2; ++nf) lB[nf] = labels[colB + nf * 16 + l15];

#pragma unroll
        for (int mf = 0; mf < 2; ++mf) {
            float gm = fmaxf(fmaxf(fmaxf(acc[mf][0][0], acc[mf][0][1]),
                                   fmaxf(acc[mf][0][2], acc[mf][0][3])),
                             fmaxf(fmaxf(acc[mf][1][0], acc[mf][1][1]),
                                   fmaxf(acc[mf][1][2], acc[mf][1][3])));
            int sk = 1;
#pragma unroll
            for (int r = 0; r < 4; ++r) sk &= (gm < mx[mf * 4 + r] - MARGIN) ? 1 : 0;
            if (!__all(sk)) {
#pragma unroll
                for (int r = 0; r < 4; ++r) {
                    const int i = mf * 4 + r;
                    float v0 = (lB[0] != labA[i]) ? acc[mf][0][r] : NEG_MASK;
                    float v1 = (lB[1] != labA[i]) ? acc[mf][1][r] : NEG_MASK;
                    float nm = fmaxf(mx[i], fmaxf(v0, v1));
                    float e  = exp2fast(v0 - nm) + exp2fast(v1 - nm);
                    sm[i] = sm[i] * exp2fast(mx[i] - nm) + e;
                    mx[i] = nm;
                }
            }
        }
    }

    // ---- intra-wave reduce across 16 column-lanes (full column set per row) ----
#pragma unroll
    for (int i = 0; i < 8; ++i) {
#pragma unroll
        for (int off = 1; off < 16; off <<= 1) {
            float m2 = __shfl_xor(mx[i], off);
            float s2 = __shfl_xor(sm[i], off);
            float nm = fmaxf(mx[i], m2);
            sm[i] = sm[i] * exp2fast(mx[i] - nm) + s2 * exp2fast(m2 - nm);
            mx[i] = nm;
        }
    }
    if (l15 == 0) {
#pragma unroll
        for (int mf = 0; mf < 2; ++mf)
#pragma unroll
            for (int r = 0; r < 4; ++r) {
                int row = wrow + mf * 16 + l16 * 4 + r;
                pmx[chunk * B_N + row] = mx[mf * 4 + r];   // base-2 units
                ps [chunk * B_N + row] = sm[mf * 4 + r];
            }
    }
}

// ---------------- per-row chunk combine + class aggregation ----------------
__global__ void classsum_kernel(const float* __restrict__ pmx, const float* __restrict__ ps,
                                const int* __restrict__ labels,
                                float* __restrict__ classSum, unsigned int* __restrict__ classCnt)
{
    __shared__ float        csL[NCLS];
    __shared__ unsigned int ccL[NCLS];
    int t = threadIdx.x;
    if (t < NCLS) { csL[t] = 0.0f; ccL[t] = 0u; }
    __syncthreads();

    int j = blockIdx.x * blockDim.x + t;
    float m = -FLT_MAX, s = 0.0f;
#pragma unroll
    for (int c = 0; c < NCHUNK; ++c) {
        float m2 = pmx[(size_t)c * B_N + j];
        float s2 = ps [(size_t)c * B_N + j];
        float nm = fmaxf(m, m2);
        s = s * exp2fast(m - nm) + s2 * exp2fast(m2 - nm);
        m = nm;
    }
    int lab = labels[j];
    atomicAdd(&csL[lab], s);
    atomicAdd(&ccL[lab], 1u);
    __syncthreads();
    if (t < NCLS) {
        atomicAdd(&classSum[t], csL[t]);
        atomicAdd(&classCnt[t], ccL[t]);
    }
}

__global__ void loss_kernel(const float* __restrict__ classSum,
                            const unsigned int* __restrict__ classCnt,
                            float* __restrict__ out)
{
    int c = threadIdx.x;  // 64 threads = 1 wave
    float cs        = (c < NCLS) ? classSum[c] : 0.0f;
    unsigned int cc = (c < NCLS) ? classCnt[c] : 0u;

    float tot = cs;
#pragma unroll
    for (int off = 1; off < 64; off <<= 1) tot += __shfl_xor(tot, off);

    float contrib = 0.0f;
    if (c < NCLS && cc > 0u) {
        float negc = (float)(B_N - (int)cc);
        float nds  = tot - cs;
        float x    = (negc > 0.0f) ? (nds / negc) : nds;
        float lp   = (cc >= 2u) ? (-logf(x + 1e-12f)) : 0.0f;
        contrib = (float)cc * lp;
    }
#pragma unroll
    for (int off = 1; off < 64; off <<= 1) contrib += __shfl_xor(contrib, off);
    if (c == 0) out[0] = -(contrib / (float)B_N);
}

extern "C" void kernel_launch(void* const* d_in, const int* in_sizes, int n_in,
                              void* d_out, int out_size, void* d_ws, size_t ws_size,
                              hipStream_t stream)
{
    const float* anchor = (const float*)d_in[0];
    const float* target = (const float*)d_in[1];
    const int*   labels = (const int*)d_in[2];
    float* out = (float*)d_out;

    const size_t PLANE = (size_t)B_N * D_KK * sizeof(short);   // 2 MB
    char* ws = (char*)d_ws;
    short* aH = (short*)(ws + 0 * PLANE);
    short* bT = (short*)(ws + 1 * PLANE);
    float* ps  = (float*)(ws + 2 * PLANE);
    float* pmx = (float*)(ws + 2 * PLANE + sizeof(float) * NCHUNK * B_N);
    char*  cls = ws + 2 * PLANE + 2 * sizeof(float) * NCHUNK * B_N;
    float*        classSum = (float*)cls;
    unsigned int* classCnt = (unsigned int*)(cls + 256);

    hipMemsetAsync(classSum, 0, 512, stream);

    prep_kernel<<<2 * (B_N * D_KK / 8) / 256, 256, 0, stream>>>(anchor, target, aH, bT);
    rowstats_kernel<<<(B_N / 128) * NCHUNK, 256, 0, stream>>>(aH, bT, labels, pmx, ps);
    classsum_kernel<<<B_N / 256, 256, 0, stream>>>(pmx, ps, labels, classSum, classCnt);
    loss_kernel<<<1, 64, 0, stream>>>(classSum, classCnt, out);
}